// Round 1
// baseline (327.152 us; speedup 1.0000x reference)
//
#include <hip/hip_runtime.h>

// Attention_73375221285454: fused MHA block on MI355X (gfx950)
// B=4 N=2048 D=768 H=12 DH=64. fp32 in/out, bf16 MFMA internally.
// Workspace layout (needs ~80.3 MB of d_ws):
//   x_bf[8192][768] bf16, WqkvT[2304][768] bf16, WoT[768][768] bf16,
//   Q/K/V[48][2048][64] bf16, Vt[48][64][2048] bf16, Aout[8192][768] bf16.

#define B_ 4
#define N_ 2048
#define D_ 768
#define H_ 12
#define DH_ 64
#define SCALE_ 0.125f

typedef __attribute__((ext_vector_type(8))) short bf8_t;   // 8 bf16 = 4 VGPRs (MFMA A/B frag)
typedef __attribute__((ext_vector_type(4))) float f4_t;    // MFMA C/D frag

__device__ __forceinline__ short f2b(float f) {            // fp32 -> bf16 RNE
  union { float f; unsigned u; } v; v.f = f;
  unsigned r = v.u + 0x7FFFu + ((v.u >> 16) & 1u);
  return (short)(r >> 16);
}

// ---------------- prep: x fp32 -> bf16 (vectorized, G13) ----------------
__global__ __launch_bounds__(256) void k_convx(const float* __restrict__ x,
                                               short* __restrict__ xb) {
  int i = blockIdx.x * 256 + threadIdx.x;
  int base = i * 8;
  float4 a = *(const float4*)(x + base);
  float4 b = *(const float4*)(x + base + 4);
  bf8_t v;
  v[0] = f2b(a.x); v[1] = f2b(a.y); v[2] = f2b(a.z); v[3] = f2b(a.w);
  v[4] = f2b(b.x); v[5] = f2b(b.y); v[6] = f2b(b.z); v[7] = f2b(b.w);
  *(bf8_t*)(xb + base) = v;
}

// ------- prep: transpose weights fp32->bf16 into B^T layout [n][k] -------
__global__ __launch_bounds__(256) void k_wtrans(const float* __restrict__ Wq,
                                                const float* __restrict__ Wk,
                                                const float* __restrict__ Wv,
                                                const float* __restrict__ Wo,
                                                short* __restrict__ WqkvT,
                                                short* __restrict__ WoT) {
  int z = blockIdx.z;
  const float* W = (z == 0) ? Wq : (z == 1) ? Wk : (z == 2) ? Wv : Wo;
  short* dst = (z < 3) ? (WqkvT + (size_t)z * D_ * D_) : WoT;
  __shared__ float T[64][65];
  int r0 = blockIdx.y * 64, c0 = blockIdx.x * 64;
  int tr = threadIdx.x >> 6, tc = threadIdx.x & 63;
#pragma unroll
  for (int i = 0; i < 16; ++i) {
    int r = tr + i * 4;
    T[r][tc] = W[(size_t)(r0 + r) * D_ + c0 + tc];
  }
  __syncthreads();
#pragma unroll
  for (int i = 0; i < 16; ++i) {
    int r = tr + i * 4;
    dst[(size_t)(c0 + r) * D_ + r0 + tc] = f2b(T[tc][r]);
  }
}

// ---------------- GEMM: C[M x Ncol] = A[M x K] * BT[Ncol x K]^T ----------------
// 128x128 tile, BK=64, 4 waves; MODE 0: QKV scatter epilogue, MODE 1: fp32 out.
template <int MODE>
__global__ __launch_bounds__(256) void k_gemm(const short* __restrict__ A,
                                              const short* __restrict__ BT, int K,
                                              short* __restrict__ Qb, short* __restrict__ Kb,
                                              short* __restrict__ Vb,
                                              float* __restrict__ Cout, int ldc) {
  __shared__ short As[128 * 72];  // +8 pad: row stride 144B -> 2-way bank alias (free)
  __shared__ short Bs[128 * 72];
  int row0 = blockIdx.y * 128, col0 = blockIdx.x * 128;
  int tid = threadIdx.x, lane = tid & 63, w = tid >> 6;
  int wr = w >> 1, wc = w & 1;
  int lr = lane & 15, lhi = lane >> 4;
  f4_t acc[4][4];
#pragma unroll
  for (int mi = 0; mi < 4; ++mi)
#pragma unroll
    for (int ni = 0; ni < 4; ++ni) acc[mi][ni] = (f4_t){0.f, 0.f, 0.f, 0.f};

  for (int k0 = 0; k0 < K; k0 += 64) {
    __syncthreads();
#pragma unroll
    for (int cc = 0; cc < 4; ++cc) {
      int c = tid + cc * 256;
      int r = c >> 3, c8 = (c & 7) * 8;
      *(bf8_t*)(As + r * 72 + c8) = *(const bf8_t*)(A + (size_t)(row0 + r) * K + k0 + c8);
    }
#pragma unroll
    for (int cc = 0; cc < 4; ++cc) {
      int c = tid + cc * 256;
      int r = c >> 3, c8 = (c & 7) * 8;
      *(bf8_t*)(Bs + r * 72 + c8) = *(const bf8_t*)(BT + (size_t)(col0 + r) * K + k0 + c8);
    }
    __syncthreads();
#pragma unroll
    for (int kc = 0; kc < 2; ++kc) {
      bf8_t av[4], bv[4];
#pragma unroll
      for (int mi = 0; mi < 4; ++mi)
        av[mi] = *(const bf8_t*)(As + (64 * wr + 16 * mi + lr) * 72 + kc * 32 + lhi * 8);
#pragma unroll
      for (int ni = 0; ni < 4; ++ni)
        bv[ni] = *(const bf8_t*)(Bs + (64 * wc + 16 * ni + lr) * 72 + kc * 32 + lhi * 8);
#pragma unroll
      for (int mi = 0; mi < 4; ++mi)
#pragma unroll
        for (int ni = 0; ni < 4; ++ni)
          acc[mi][ni] = __builtin_amdgcn_mfma_f32_16x16x32_bf16(av[mi], bv[ni], acc[mi][ni], 0, 0, 0);
    }
  }
  // epilogue (C/D layout: col = lane&15, row = (lane>>4)*4 + reg  [m89])
#pragma unroll
  for (int mi = 0; mi < 4; ++mi)
#pragma unroll
    for (int ni = 0; ni < 4; ++ni)
#pragma unroll
      for (int r = 0; r < 4; ++r) {
        int row = row0 + 64 * wr + 16 * mi + 4 * lhi + r;
        int col = col0 + 64 * wc + 16 * ni + lr;
        float v = acc[mi][ni][r];
        if (MODE == 0) {
          int which = col / 768;
          int cc2 = col - which * 768;
          int h = cc2 >> 6, dh = cc2 & 63;
          int b = row >> 11, n = row & 2047;
          size_t dst = (((size_t)(b * H_ + h)) * N_ + n) * DH_ + dh;
          short bv2 = f2b(v);
          if (which == 0) Qb[dst] = bv2;
          else if (which == 1) Kb[dst] = bv2;
          else Vb[dst] = bv2;
        } else {
          Cout[(size_t)row * ldc + col] = v;
        }
      }
}

// ---------------- V[bh][n][dh] -> Vt[bh][dh][n] (LDS tile transpose) ----------------
__global__ __launch_bounds__(256) void k_vtrans(const short* __restrict__ V,
                                                short* __restrict__ Vt) {
  int bh = blockIdx.y;
  int n0 = blockIdx.x * 64;
  __shared__ short T[64][72];
  int tr = threadIdx.x >> 6, tc = threadIdx.x & 63;
  const short* Vp = V + (size_t)bh * N_ * DH_;
  short* Vtp = Vt + (size_t)bh * DH_ * N_;
#pragma unroll
  for (int i = 0; i < 16; ++i) {
    int r = tr + i * 4;
    T[r][tc] = Vp[(size_t)(n0 + r) * DH_ + tc];
  }
  __syncthreads();
#pragma unroll
  for (int i = 0; i < 16; ++i) {
    int r = tr + i * 4;
    Vtp[(size_t)r * N_ + n0 + tc] = T[tc][r];
  }
}

// ---------------- flash attention: 128 q-rows/block, kv tiles of 128 ----------------
__global__ __launch_bounds__(256) void k_attn(const short* __restrict__ Q,
                                              const short* __restrict__ Kg,
                                              const short* __restrict__ Vtg,
                                              const int* __restrict__ xmask,
                                              short* __restrict__ Aout) {
  int bh = blockIdx.y;
  int b = bh / H_, h = bh - b * H_;
  const short* Qp = Q + (size_t)bh * N_ * DH_;
  const short* Kp = Kg + (size_t)bh * N_ * DH_;
  const short* Vp = Vtg + (size_t)bh * DH_ * N_;
  const int* mk = xmask + b * N_;
  int q0 = blockIdx.x * 128;
  int tid = threadIdx.x, lane = tid & 63, w = tid >> 6;
  int lr = lane & 15, lhi = lane >> 4;

  // Ps (17408 shorts) overlays Ks (9216 shorts): K-tile dead once QK^T done.
  __shared__ short smem[128 * 136 + 64 * 136];  // 52224 B
  short* Ps = smem;
  short* Ks = smem;
  short* Vs = smem + 128 * 136;

  bf8_t qf[2][2];  // Q frags hoisted to registers
#pragma unroll
  for (int mi = 0; mi < 2; ++mi)
#pragma unroll
    for (int kc = 0; kc < 2; ++kc)
      qf[mi][kc] = *(const bf8_t*)(Qp + (size_t)(q0 + 32 * w + 16 * mi + lr) * DH_ + kc * 32 + lhi * 8);

  float qmv[2][4];
#pragma unroll
  for (int mi = 0; mi < 2; ++mi)
#pragma unroll
    for (int r = 0; r < 4; ++r)
      qmv[mi][r] = mk[q0 + 32 * w + 16 * mi + 4 * lhi + r] ? 1.f : 0.f;

  f4_t oacc[2][4];
  float mrow[2][4], lrow[2][4];
#pragma unroll
  for (int mi = 0; mi < 2; ++mi) {
#pragma unroll
    for (int nd = 0; nd < 4; ++nd) oacc[mi][nd] = (f4_t){0.f, 0.f, 0.f, 0.f};
#pragma unroll
    for (int r = 0; r < 4; ++r) { mrow[mi][r] = -1e30f; lrow[mi][r] = 0.f; }
  }

  for (int kt = 0; kt < 16; ++kt) {
    int key0 = kt * 128;
#pragma unroll
    for (int cc = 0; cc < 4; ++cc) {  // stage K tile [128 keys][64 dh] -> Ks[key][72]
      int c = tid + cc * 256;
      int r = c >> 3, c8 = (c & 7) * 8;
      *(bf8_t*)(Ks + r * 72 + c8) = *(const bf8_t*)(Kp + (size_t)(key0 + r) * DH_ + c8);
    }
#pragma unroll
    for (int cc = 0; cc < 4; ++cc) {  // stage Vt tile [64 dh][128 keys] -> Vs[dh][136]
      int c = tid + cc * 256;
      int r = c >> 4, c8 = (c & 15) * 8;
      *(bf8_t*)(Vs + r * 136 + c8) = *(const bf8_t*)(Vp + (size_t)r * N_ + key0 + c8);
    }
    __syncthreads();

    f4_t sacc[2][8];
#pragma unroll
    for (int mi = 0; mi < 2; ++mi)
#pragma unroll
      for (int ni = 0; ni < 8; ++ni) sacc[mi][ni] = (f4_t){0.f, 0.f, 0.f, 0.f};
#pragma unroll
    for (int kc = 0; kc < 2; ++kc) {
      bf8_t bv[8];
#pragma unroll
      for (int ni = 0; ni < 8; ++ni)
        bv[ni] = *(const bf8_t*)(Ks + (16 * ni + lr) * 72 + kc * 32 + lhi * 8);
#pragma unroll
      for (int mi = 0; mi < 2; ++mi)
#pragma unroll
        for (int ni = 0; ni < 8; ++ni)
          sacc[mi][ni] = __builtin_amdgcn_mfma_f32_16x16x32_bf16(qf[mi][kc], bv[ni], sacc[mi][ni], 0, 0, 0);
    }
    __syncthreads();  // all waves done reading Ks -> safe to overwrite with Ps

    float kmv[8];
#pragma unroll
    for (int ni = 0; ni < 8; ++ni) kmv[ni] = mk[key0 + 16 * ni + lr] ? 1.f : 0.f;

#pragma unroll
    for (int mi = 0; mi < 2; ++mi) {
      float sv[8][4];
      float mx[4] = {-1e30f, -1e30f, -1e30f, -1e30f};
#pragma unroll
      for (int ni = 0; ni < 8; ++ni)
#pragma unroll
        for (int r = 0; r < 4; ++r) {
          float s = sacc[mi][ni][r] * SCALE_;
          s = (kmv[ni] != 0.f) ? s : -1e30f;   // masked key
          s = (qmv[mi][r] != 0.f) ? s : 0.f;   // masked query row -> uniform softmax
          sv[ni][r] = s;
          mx[r] = fmaxf(mx[r], s);
        }
#pragma unroll
      for (int r = 0; r < 4; ++r) {
#pragma unroll
        for (int off = 1; off < 16; off <<= 1) mx[r] = fmaxf(mx[r], __shfl_xor(mx[r], off));
        float mn = fmaxf(mrow[mi][r], mx[r]);
        float sc = __expf(mrow[mi][r] - mn);
        mrow[mi][r] = mn;
        float ps = 0.f;
#pragma unroll
        for (int ni = 0; ni < 8; ++ni) {
          float p = __expf(sv[ni][r] - mn);
          ps += p;
          Ps[(32 * w + 16 * mi + 4 * lhi + r) * 136 + 16 * ni + lr] = f2b(p);
        }
        lrow[mi][r] = lrow[mi][r] * sc + ps;
#pragma unroll
        for (int nd = 0; nd < 4; ++nd) oacc[mi][nd][r] *= sc;
      }
    }
    __syncthreads();  // P writes visible before PV reads

#pragma unroll
    for (int kc2 = 0; kc2 < 4; ++kc2) {
      bf8_t pa[2], vb2[4];
#pragma unroll
      for (int mi = 0; mi < 2; ++mi)
        pa[mi] = *(const bf8_t*)(Ps + (32 * w + 16 * mi + lr) * 136 + kc2 * 32 + lhi * 8);
#pragma unroll
      for (int nd = 0; nd < 4; ++nd)
        vb2[nd] = *(const bf8_t*)(Vs + (16 * nd + lr) * 136 + kc2 * 32 + lhi * 8);
#pragma unroll
      for (int mi = 0; mi < 2; ++mi)
#pragma unroll
        for (int nd = 0; nd < 4; ++nd)
          oacc[mi][nd] = __builtin_amdgcn_mfma_f32_16x16x32_bf16(pa[mi], vb2[nd], oacc[mi][nd], 0, 0, 0);
    }
    __syncthreads();  // protect Ks/Vs/Ps restage next iteration
  }

#pragma unroll
  for (int mi = 0; mi < 2; ++mi)
#pragma unroll
    for (int r = 0; r < 4; ++r) {
      float s = lrow[mi][r];
#pragma unroll
      for (int off = 1; off < 16; off <<= 1) s += __shfl_xor(s, off);
      float inv = 1.f / s;
      int n = q0 + 32 * w + 16 * mi + 4 * lhi + r;
#pragma unroll
      for (int nd = 0; nd < 4; ++nd)
        Aout[((size_t)b * N_ + n) * D_ + h * DH_ + 16 * nd + lr] = f2b(oacc[mi][nd][r] * inv);
    }
}

extern "C" void kernel_launch(void* const* d_in, const int* in_sizes, int n_in,
                              void* d_out, int out_size, void* d_ws, size_t ws_size,
                              hipStream_t stream) {
  (void)in_sizes; (void)n_in; (void)out_size; (void)ws_size;
  const float* x  = (const float*)d_in[0];
  const int*   xm = (const int*)d_in[1];
  const float* Wq = (const float*)d_in[2];
  const float* Wk = (const float*)d_in[3];
  const float* Wv = (const float*)d_in[4];
  const float* Wo = (const float*)d_in[5];
  float* out = (float*)d_out;
  char* ws = (char*)d_ws;

  short* x_bf  = (short*)(ws + 0);         // 12,582,912 B
  short* WqkvT = (short*)(ws + 12582912);  //  3,538,944 B
  short* WoT   = (short*)(ws + 16121856);  //  1,179,648 B
  short* Qb    = (short*)(ws + 17301504);  // 12,582,912 B
  short* Kb    = (short*)(ws + 29884416);  // 12,582,912 B
  short* Vb    = (short*)(ws + 42467328);  // 12,582,912 B
  short* Vt    = (short*)(ws + 55050240);  // 12,582,912 B
  short* Ao    = (short*)(ws + 67633152);  // 12,582,912 B  (total 80,216,064 B)

  k_convx<<<3072, 256, 0, stream>>>(x, x_bf);
  k_wtrans<<<dim3(12, 12, 4), 256, 0, stream>>>(Wq, Wk, Wv, Wo, WqkvT, WoT);
  k_gemm<0><<<dim3(18, 64), 256, 0, stream>>>(x_bf, WqkvT, 768, Qb, Kb, Vb, nullptr, 0);
  k_vtrans<<<dim3(32, 48), 256, 0, stream>>>(Vb, Vt);
  k_attn<<<dim3(16, 48), 256, 0, stream>>>(Qb, Kb, Vt, xm, Ao);
  k_gemm<1><<<dim3(6, 64), 256, 0, stream>>>(Ao, WoT, 768, nullptr, nullptr, nullptr, out, 768);
}

// Round 2
// 178.264 us; speedup vs baseline: 1.8352x; 1.8352x over previous
//
#include <hip/hip_runtime.h>

// Attention_73375221285454: fused MHA block on MI355X (gfx950)
// B=4 N=2048 D=768 H=12 DH=64. fp32 in/out, bf16 MFMA internally.
// Round 2: k_attn rewritten as swapped-QK^T 32x32 flash attention (m214
// structure): per-lane softmax, cvt_pk+permlane32_swap P redistribution,
// XOR-swizzled K/V LDS tiles via global_load_lds, 1 barrier per KV tile.

#define B_ 4
#define N_ 2048
#define D_ 768
#define H_ 12
#define DH_ 64
#define CSC_ 0.18033688011112042f  // SCALE * log2(e) = 0.125 * 1.4426950408889634

typedef __attribute__((ext_vector_type(8))) short bf8_t;   // 8 bf16 (MFMA A/B frag)
typedef __attribute__((ext_vector_type(4))) float f4_t;    // 16x16 C/D frag
typedef __attribute__((ext_vector_type(16))) float f16v;   // 32x32 C/D frag
typedef __attribute__((ext_vector_type(4))) int i4_t;

__device__ __forceinline__ short f2b(float f) {            // fp32 -> bf16 RNE
  union { float f; unsigned u; } v; v.f = f;
  unsigned r = v.u + 0x7FFFu + ((v.u >> 16) & 1u);
  return (short)(r >> 16);
}

__device__ __forceinline__ unsigned cvtpk(float lo, float hi) {
  unsigned r;
  asm("v_cvt_pk_bf16_f32 %0, %1, %2" : "=v"(r) : "v"(lo), "v"(hi));
  return r;
}

__device__ __forceinline__ void plswap(unsigned& a, unsigned& b) {
  // after: a = {a.lo32lanes, b.lo32lanes}, b = {a.hi32lanes, b.hi32lanes}
  asm("v_permlane32_swap_b32 %0, %1" : "+v"(a), "+v"(b));
}

#define GLOAD_LDS16(gp, lp)                                                       \
  __builtin_amdgcn_global_load_lds(                                               \
      (const __attribute__((address_space(1))) void*)(gp),                        \
      (__attribute__((address_space(3))) void*)(lp), 16, 0, 0)

// ---------------- prep: x fp32 -> bf16 (vectorized) ----------------
__global__ __launch_bounds__(256) void k_convx(const float* __restrict__ x,
                                               short* __restrict__ xb) {
  int i = blockIdx.x * 256 + threadIdx.x;
  int base = i * 8;
  float4 a = *(const float4*)(x + base);
  float4 b = *(const float4*)(x + base + 4);
  bf8_t v;
  v[0] = f2b(a.x); v[1] = f2b(a.y); v[2] = f2b(a.z); v[3] = f2b(a.w);
  v[4] = f2b(b.x); v[5] = f2b(b.y); v[6] = f2b(b.z); v[7] = f2b(b.w);
  *(bf8_t*)(xb + base) = v;
}

// ------- prep: transpose weights fp32->bf16 into B^T layout [n][k] -------
__global__ __launch_bounds__(256) void k_wtrans(const float* __restrict__ Wq,
                                                const float* __restrict__ Wk,
                                                const float* __restrict__ Wv,
                                                const float* __restrict__ Wo,
                                                short* __restrict__ WqkvT,
                                                short* __restrict__ WoT) {
  int z = blockIdx.z;
  const float* W = (z == 0) ? Wq : (z == 1) ? Wk : (z == 2) ? Wv : Wo;
  short* dst = (z < 3) ? (WqkvT + (size_t)z * D_ * D_) : WoT;
  __shared__ float T[64][65];
  int r0 = blockIdx.y * 64, c0 = blockIdx.x * 64;
  int tr = threadIdx.x >> 6, tc = threadIdx.x & 63;
#pragma unroll
  for (int i = 0; i < 16; ++i) {
    int r = tr + i * 4;
    T[r][tc] = W[(size_t)(r0 + r) * D_ + c0 + tc];
  }
  __syncthreads();
#pragma unroll
  for (int i = 0; i < 16; ++i) {
    int r = tr + i * 4;
    dst[(size_t)(c0 + r) * D_ + r0 + tc] = f2b(T[tc][r]);
  }
}

// ---------------- GEMM: C[M x Ncol] = A[M x K] * BT[Ncol x K]^T ----------------
template <int MODE>
__global__ __launch_bounds__(256) void k_gemm(const short* __restrict__ A,
                                              const short* __restrict__ BT, int K,
                                              short* __restrict__ Qb, short* __restrict__ Kb,
                                              short* __restrict__ Vb,
                                              float* __restrict__ Cout, int ldc) {
  __shared__ short As[128 * 72];
  __shared__ short Bs[128 * 72];
  int row0 = blockIdx.y * 128, col0 = blockIdx.x * 128;
  int tid = threadIdx.x, lane = tid & 63, w = tid >> 6;
  int wr = w >> 1, wc = w & 1;
  int lr = lane & 15, lhi = lane >> 4;
  f4_t acc[4][4];
#pragma unroll
  for (int mi = 0; mi < 4; ++mi)
#pragma unroll
    for (int ni = 0; ni < 4; ++ni) acc[mi][ni] = (f4_t){0.f, 0.f, 0.f, 0.f};

  for (int k0 = 0; k0 < K; k0 += 64) {
    __syncthreads();
#pragma unroll
    for (int cc = 0; cc < 4; ++cc) {
      int c = tid + cc * 256;
      int r = c >> 3, c8 = (c & 7) * 8;
      *(bf8_t*)(As + r * 72 + c8) = *(const bf8_t*)(A + (size_t)(row0 + r) * K + k0 + c8);
    }
#pragma unroll
    for (int cc = 0; cc < 4; ++cc) {
      int c = tid + cc * 256;
      int r = c >> 3, c8 = (c & 7) * 8;
      *(bf8_t*)(Bs + r * 72 + c8) = *(const bf8_t*)(BT + (size_t)(col0 + r) * K + k0 + c8);
    }
    __syncthreads();
#pragma unroll
    for (int kc = 0; kc < 2; ++kc) {
      bf8_t av[4], bv[4];
#pragma unroll
      for (int mi = 0; mi < 4; ++mi)
        av[mi] = *(const bf8_t*)(As + (64 * wr + 16 * mi + lr) * 72 + kc * 32 + lhi * 8);
#pragma unroll
      for (int ni = 0; ni < 4; ++ni)
        bv[ni] = *(const bf8_t*)(Bs + (64 * wc + 16 * ni + lr) * 72 + kc * 32 + lhi * 8);
#pragma unroll
      for (int mi = 0; mi < 4; ++mi)
#pragma unroll
        for (int ni = 0; ni < 4; ++ni)
          acc[mi][ni] = __builtin_amdgcn_mfma_f32_16x16x32_bf16(av[mi], bv[ni], acc[mi][ni], 0, 0, 0);
    }
  }
#pragma unroll
  for (int mi = 0; mi < 4; ++mi)
#pragma unroll
    for (int ni = 0; ni < 4; ++ni)
#pragma unroll
      for (int r = 0; r < 4; ++r) {
        int row = row0 + 64 * wr + 16 * mi + 4 * lhi + r;
        int col = col0 + 64 * wc + 16 * ni + lr;
        float v = acc[mi][ni][r];
        if (MODE == 0) {
          int which = col / 768;
          int cc2 = col - which * 768;
          int h = cc2 >> 6, dh = cc2 & 63;
          int b = row >> 11, n = row & 2047;
          size_t dst = (((size_t)(b * H_ + h)) * N_ + n) * DH_ + dh;
          short bv2 = f2b(v);
          if (which == 0) Qb[dst] = bv2;
          else if (which == 1) Kb[dst] = bv2;
          else Vb[dst] = bv2;
        } else {
          Cout[(size_t)row * ldc + col] = v;
        }
      }
}

// ---------------- V[bh][n][dh] -> Vt[bh][dh][n] ----------------
__global__ __launch_bounds__(256) void k_vtrans(const short* __restrict__ V,
                                                short* __restrict__ Vt) {
  int bh = blockIdx.y;
  int n0 = blockIdx.x * 64;
  __shared__ short T[64][72];
  int tr = threadIdx.x >> 6, tc = threadIdx.x & 63;
  const short* Vp = V + (size_t)bh * N_ * DH_;
  short* Vtp = Vt + (size_t)bh * DH_ * N_;
#pragma unroll
  for (int i = 0; i < 16; ++i) {
    int r = tr + i * 4;
    T[r][tc] = Vp[(size_t)(n0 + r) * DH_ + tc];
  }
  __syncthreads();
#pragma unroll
  for (int i = 0; i < 16; ++i) {
    int r = tr + i * 4;
    Vtp[(size_t)r * N_ + n0 + tc] = T[tc][r];
  }
}

// -------- flash attention, swapped-QK^T 32x32 (m214 structure) --------
// 4 warps x 32 q-rows = 128 q/block; KVBLK=64; K/V LDS double-buffered,
// XOR-swizzled; softmax fully in-register (lane owns q = lane&31).
__global__ __launch_bounds__(256, 3) void k_attn(const short* __restrict__ Q,
                                                 const short* __restrict__ Kg,
                                                 const short* __restrict__ Vtg,
                                                 const int* __restrict__ xmask,
                                                 short* __restrict__ Aout) {
  int bh = blockIdx.y;
  int b = bh / H_, h = bh - b * H_;
  const short* Qp = Q + (size_t)bh * N_ * DH_;
  const short* Kp = Kg + (size_t)bh * N_ * DH_;
  const short* Vp = Vtg + (size_t)bh * DH_ * N_;
  const int* mk = xmask + b * N_;
  int q0 = blockIdx.x * 128;
  int tid = threadIdx.x, lane = tid & 63, w = tid >> 6;
  int lq = lane & 31, hi = lane >> 5;

  __shared__ char smem[32768];  // 2 x (K 8KB + V 8KB); epilogue reuses 4x4608B

  // Q fragments: B-operand of mfma(K,Q): lane holds Q[q0+32w+lq][16kc+8hi..+8]
  bf8_t qf[4];
#pragma unroll
  for (int kc = 0; kc < 4; ++kc)
    qf[kc] = *(const bf8_t*)(Qp + (size_t)(q0 + 32 * w + lq) * DH_ + 16 * kc + 8 * hi);

  int qm = mk[q0 + 32 * w + lq];  // per-lane q mask (lane-uniform per q)

  f16v acco[2];
#pragma unroll
  for (int i = 0; i < 16; ++i) { acco[0][i] = 0.f; acco[1][i] = 0.f; }
  float m = -1e30f, lsum = 0.f;

  // stage tile kt into buf: K[key][dh] and Vt[dh][key], 64x128B rows each,
  // XOR-swizzle applied on the GLOBAL source (LDS dest linear, rule #21).
  auto STAGE = [&](int key0, int buf) {
    char* kb_ = smem + buf * 16384;
    char* vb_ = kb_ + 8192;
    int row = tid >> 3;
    int cb = (tid & 7) * 16;
    char* lk = kb_ + ((tid >> 6) << 10);
    char* lv = vb_ + ((tid >> 6) << 10);
#pragma unroll
    for (int rr = 0; rr < 2; ++rr) {
      int r2 = row + rr * 32;
      int sw = cb ^ ((r2 & 7) << 4);
      GLOAD_LDS16((const char*)(Kp + (size_t)(key0 + r2) * DH_) + sw, lk + rr * 4096);
      GLOAD_LDS16((const char*)(Vp + (size_t)r2 * N_ + key0) + sw, lv + rr * 4096);
    }
  };

  STAGE(0, 0);
  __syncthreads();

  for (int kt = 0; kt < N_ / 64; ++kt) {
    int cur = kt & 1;
    if (kt + 1 < N_ / 64) STAGE((kt + 1) * 64, cur ^ 1);  // async, overlaps compute

    const char* kbase = smem + cur * 16384;
    const char* vbase = kbase + 8192;
    int key0 = kt * 64;

    // ---- QK^T: S^T[key][q], acc[kb] keys 32kb + (r&3)+8*(r>>2)+4*hi ----
    f16v accs[2];
#pragma unroll
    for (int i = 0; i < 16; ++i) { accs[0][i] = 0.f; accs[1][i] = 0.f; }
    int swz = (lq & 7) << 4;
#pragma unroll
    for (int kc = 0; kc < 4; ++kc) {
      int colb = (32 * kc + 16 * hi) ^ swz;
      bf8_t k0 = *(const bf8_t*)(kbase + lq * 128 + colb);
      bf8_t k1 = *(const bf8_t*)(kbase + (32 + lq) * 128 + colb);
      accs[0] = __builtin_amdgcn_mfma_f32_32x32x16_bf16(k0, qf[kc], accs[0], 0, 0, 0);
      accs[1] = __builtin_amdgcn_mfma_f32_32x32x16_bf16(k1, qf[kc], accs[1], 0, 0, 0);
    }

    // ---- masks ----
    unsigned long long bm = __ballot(mk[key0 + lane] != 0);
    unsigned bs[2];
    bs[0] = ((unsigned)bm) >> (4 * hi);
    bs[1] = ((unsigned)(bm >> 32)) >> (4 * hi);

    // ---- per-lane online softmax (q = lq) ----
    float mxa[4] = {-1e30f, -1e30f, -1e30f, -1e30f};
#pragma unroll
    for (int kb2 = 0; kb2 < 2; ++kb2)
#pragma unroll
      for (int r = 0; r < 16; ++r) {
        float sl = accs[kb2][r] * CSC_;
        int bit = (bs[kb2] >> ((r & 3) + 8 * (r >> 2))) & 1;
        sl = bit ? sl : -1e30f;
        sl = qm ? sl : 0.f;
        accs[kb2][r] = sl;
        mxa[r & 3] = fmaxf(mxa[r & 3], sl);
      }
    float mx = fmaxf(fmaxf(mxa[0], mxa[1]), fmaxf(mxa[2], mxa[3]));
    mx = fmaxf(mx, __shfl_xor(mx, 32));
    float mnew = fmaxf(m, mx);
    float sc = __builtin_amdgcn_exp2f(m - mnew);
    m = mnew;
    float psa[4] = {0.f, 0.f, 0.f, 0.f};
#pragma unroll
    for (int kb2 = 0; kb2 < 2; ++kb2)
#pragma unroll
      for (int r = 0; r < 16; ++r) {
        float p = __builtin_amdgcn_exp2f(accs[kb2][r] - mnew);
        accs[kb2][r] = p;
        psa[r & 3] += p;
      }
    float ps = (psa[0] + psa[1]) + (psa[2] + psa[3]);
    ps += __shfl_xor(ps, 32);
    lsum = lsum * sc + ps;
#pragma unroll
    for (int i = 0; i < 16; ++i) { acco[0][i] *= sc; acco[1][i] *= sc; }

    // ---- PV: O^T += V^T * P^T; P frags via cvt_pk + permlane32_swap ----
#pragma unroll
    for (int kc = 0; kc < 4; ++kc) {
      int kb2 = kc >> 1, rb = (kc & 1) * 8;
      unsigned a_ = cvtpk(accs[kb2][rb + 0], accs[kb2][rb + 1]);
      unsigned b_ = cvtpk(accs[kb2][rb + 4], accs[kb2][rb + 5]);
      unsigned c_ = cvtpk(accs[kb2][rb + 2], accs[kb2][rb + 3]);
      unsigned d_ = cvtpk(accs[kb2][rb + 6], accs[kb2][rb + 7]);
      plswap(a_, b_);
      plswap(c_, d_);
      union { i4_t i; bf8_t v; } pu;
      pu.i = (i4_t){(int)a_, (int)c_, (int)b_, (int)d_};
      int colb = (32 * kc + 16 * hi) ^ swz;
      bf8_t v0 = *(const bf8_t*)(vbase + lq * 128 + colb);
      bf8_t v1 = *(const bf8_t*)(vbase + (32 + lq) * 128 + colb);
      acco[0] = __builtin_amdgcn_mfma_f32_32x32x16_bf16(v0, pu.v, acco[0], 0, 0, 0);
      acco[1] = __builtin_amdgcn_mfma_f32_32x32x16_bf16(v1, pu.v, acco[1], 0, 0, 0);
    }

    __syncthreads();  // drains this iter's STAGE loads; publishes buf^1
  }

  // ---- epilogue: O^T -> LDS transpose (per-warp region) -> coalesced store ----
  float inv = 1.f / lsum;
  unsigned* Os = (unsigned*)smem + w * 1152;  // 32 rows x 36 u32 (16B-aligned rows)
#pragma unroll
  for (int dhb = 0; dhb < 2; ++dhb)
#pragma unroll
    for (int r = 0; r < 16; r += 2) {
      unsigned pk = cvtpk(acco[dhb][r] * inv, acco[dhb][r + 1] * inv);
      int colu = 16 * dhb + ((r & 3) >> 1) + 4 * (r >> 2) + 2 * hi;
      Os[lq * 36 + colu] = pk;
    }
#pragma unroll
  for (int it = 0; it < 4; ++it) {
    int q = (lane >> 3) + 8 * it;
    i4_t vv = *(const i4_t*)(Os + q * 36 + 4 * (lane & 7));
    union { i4_t i; bf8_t s; } u2;
    u2.i = vv;
    size_t off = ((size_t)b * N_ + q0 + 32 * w + q) * D_ + h * DH_ + 8 * (lane & 7);
    *(bf8_t*)(Aout + off) = u2.s;
  }
}

extern "C" void kernel_launch(void* const* d_in, const int* in_sizes, int n_in,
                              void* d_out, int out_size, void* d_ws, size_t ws_size,
                              hipStream_t stream) {
  (void)in_sizes; (void)n_in; (void)out_size; (void)ws_size;
  const float* x  = (const float*)d_in[0];
  const int*   xm = (const int*)d_in[1];
  const float* Wq = (const float*)d_in[2];
  const float* Wk = (const float*)d_in[3];
  const float* Wv = (const float*)d_in[4];
  const float* Wo = (const float*)d_in[5];
  float* out = (float*)d_out;
  char* ws = (char*)d_ws;

  short* x_bf  = (short*)(ws + 0);
  short* WqkvT = (short*)(ws + 12582912);
  short* WoT   = (short*)(ws + 16121856);
  short* Qb    = (short*)(ws + 17301504);
  short* Kb    = (short*)(ws + 29884416);
  short* Vb    = (short*)(ws + 42467328);
  short* Vt    = (short*)(ws + 55050240);
  short* Ao    = (short*)(ws + 67633152);

  k_convx<<<3072, 256, 0, stream>>>(x, x_bf);
  k_wtrans<<<dim3(12, 12, 4), 256, 0, stream>>>(Wq, Wk, Wv, Wo, WqkvT, WoT);
  k_gemm<0><<<dim3(18, 64), 256, 0, stream>>>(x_bf, WqkvT, 768, Qb, Kb, Vb, nullptr, 0);
  k_vtrans<<<dim3(32, 48), 256, 0, stream>>>(Vb, Vt);
  k_attn<<<dim3(16, 48), 256, 0, stream>>>(Qb, Kb, Vt, xm, Ao);
  k_gemm<1><<<dim3(6, 64), 256, 0, stream>>>(Ao, WoT, 768, nullptr, nullptr, nullptr, out, 768);
}